// Round 20
// baseline (67.266 us; speedup 1.0000x reference)
//
#include <hip/hip_runtime.h>
#include <math.h>
#include <stdint.h>

#define NB 64
#define NL 3168
#define NC 64
#define ND 512
#define NK 16
#define NW 198
#define NM 12672   // NB*NW rows
#define KD 1024    // contraction dim; layout (c>>2)*64 + k*4 + (c&3) for val/wdeft

typedef __attribute__((ext_vector_type(8))) short bf8_t;   // 8 bf16 (4 VGPR) MFMA A/B frag
typedef __attribute__((ext_vector_type(4))) float f4_t;    // MFMA C/D frag

typedef const unsigned int __attribute__((address_space(1)))* as1_u32p;
typedef unsigned int __attribute__((address_space(3)))* as3_u32p;

__device__ __forceinline__ void gl_lds16(const void* g, void* l) {
  // global -> LDS direct DMA, 16B per lane. LDS dest = wave-uniform base + lane*16.
  __builtin_amdgcn_global_load_lds((as1_u32p)(uintptr_t)g,
                                   (as3_u32p)(unsigned int)(uintptr_t)l, 16, 0, 0);
}

__device__ __forceinline__ unsigned short f2bf(float f) {
  union { float f; unsigned u; } v; v.f = f;
  unsigned r = v.u + 0x7FFFu + ((v.u >> 16) & 1u);
  return (unsigned short)(r >> 16);
}

// ---------------------------------------------------------------------------
// prep: wdeft[d][(c>>2)*64+k*4+(c&3)] = bf16(w_def[d][c][k]) -- permuted cast;
//       wofft[o][k*64+c] (phase-1 layout, matches x's natural k-major order);
//       pe table (f32); cls rows.
// ---------------------------------------------------------------------------
__global__ void prep_kernel(const float* __restrict__ w_off, const float* __restrict__ w_def,
                            const float* __restrict__ cls, unsigned short* __restrict__ wofft,
                            unsigned short* __restrict__ wdeft, float* __restrict__ pe,
                            float* __restrict__ out) {
  int id = blockIdx.x * 256 + threadIdx.x;
  if (id < 131072) {   // one float4 of w_def: elements (d, c, k0..k0+3)
    float4 v = ((const float4*)w_def)[id];
    int e = id * 4;
    int d = e >> 10, c = (e >> 4) & 63, k0 = e & 15;
    unsigned short* dst = wdeft + d * 1024 + (c >> 2) * 64 + k0 * 4 + (c & 3);
    dst[0] = f2bf(v.x); dst[4] = f2bf(v.y); dst[8] = f2bf(v.z); dst[12] = f2bf(v.w);
    return;
  }
  id -= 131072;
  if (id < 32768) {
    int o = id >> 10, kc = id & 1023, k = kc >> 6, c = kc & 63;
    wofft[id] = f2bf(w_off[o * 1024 + c * 16 + k]);
    return;
  }
  id -= 32768;
  if (id < 101888) {   // 199 * 512 positional-encoding table
    int pos = id >> 9, d = id & 511;
    int i = d >> 1;
    float freq = expf((float)(2 * i) * (-9.210340371976184f / 512.0f));
    float arg = (float)pos * freq;
    pe[id] = (d & 1) ? cosf(arg) : sinf(arg);
    return;
  }
  id -= 101888;
  {  // cls rows: out[b][0][d] = cls[d] + pe[0][d]
    int b = id >> 9, d = id & 511;
    out[(size_t)(b * 199) * 512 + d] = cls[d] + ((d & 1) ? 1.0f : 0.0f);
  }
}

// ---------------------------------------------------------------------------
// fused off-GEMM + sampling: 792 blocks x 512 thr, matched XCD swizzle
// b=(flat&7)*99+(flat>>3) (R17). Phase 1/1.5 = R17-exact. Phase 2 VECTORIZED:
// lane l = (c4=l>>2, kq=l&3); pass p handles k=p*4+kq; each lane loads float4
// (4 channels) per gather row -> 8 float4 loads/row instead of 32 scalar
// floats (4x fewer load instructions, same bytes, L2-hot). Output layout
// (c4,k,cl) makes each 4-lane group's 8B stores 32B-contiguous.
// ---------------------------------------------------------------------------
__launch_bounds__(512)
__global__ void offsample_kernel(const float* __restrict__ x,
                                 const unsigned short* __restrict__ wofft,
                                 const float* __restrict__ b_off,
                                 unsigned short* __restrict__ val_ws) {
  __shared__ float partial[8][16][33];
  __shared__ float2 s_w[16][16];   // (w0, w1) per (row, k): bounds folded in
  __shared__ int2   s_i[16][16];   // (x0c*64, x1c*64) clamped gather offsets
  __shared__ int    s_base[16];    // b * NL * NC per row
  int tid = threadIdx.x;
  int lane = tid & 63, wid = tid >> 6;              // wid 0..7
  int r16 = lane & 15, kg = lane >> 4;
  int flat = blockIdx.x;                            // 0..791
  int bsw = (flat & 7) * 99 + (flat >> 3);          // bijective; matches gemm's XCD map
  int row0 = bsw * 16;

  f4_t acc[2] = {};
  const float* arow = x + (size_t)(row0 + r16) * KD + wid * 128;   // lane's A row, K-slice
  const unsigned short* bcol0 = wofft + r16 * KD + wid * 128;
  const unsigned short* bcol1 = wofft + (16 + r16) * KD + wid * 128;

#pragma unroll
  for (int ks = 0; ks < 4; ++ks) {
    int k0 = ks * 32 + kg * 8;
    float4 v0 = *(const float4*)(arow + k0);
    float4 v1 = *(const float4*)(arow + k0 + 4);
    bf8_t a;
    a[0] = (short)f2bf(v0.x); a[1] = (short)f2bf(v0.y);
    a[2] = (short)f2bf(v0.z); a[3] = (short)f2bf(v0.w);
    a[4] = (short)f2bf(v1.x); a[5] = (short)f2bf(v1.y);
    a[6] = (short)f2bf(v1.z); a[7] = (short)f2bf(v1.w);
    bf8_t b0 = *(const bf8_t*)(bcol0 + k0);
    bf8_t b1 = *(const bf8_t*)(bcol1 + k0);
    acc[0] = __builtin_amdgcn_mfma_f32_16x16x32_bf16(a, b0, acc[0], 0, 0, 0);
    acc[1] = __builtin_amdgcn_mfma_f32_16x16x32_bf16(a, b1, acc[1], 0, 0, 0);
  }
  // C layout: col = lane&15 (B col), row = kg*4 + reg (A row)
#pragma unroll
  for (int n = 0; n < 2; ++n)
#pragma unroll
    for (int r = 0; r < 4; ++r)
      partial[wid][kg * 4 + r][n * 16 + r16] = acc[n][r];
  __syncthreads();

  // Phase 1.5: one thread per (row, k) unit.
  if (tid < 256) {
    int rp = tid >> 4, k = tid & 15;
    float dy = b_off[2 * k], dx = b_off[2 * k + 1];
#pragma unroll
    for (int w8 = 0; w8 < 8; ++w8) {
      dy += partial[w8][rp][2 * k];
      dx += partial[w8][rp][2 * k + 1];
    }
    int rg = row0 + rp;
    int b = rg / NW, w = rg - b * NW;
    if (k == 0) s_base[rp] = b * (NL * NC);
    float wy = fmaxf(0.f, 1.f - fabsf(dy));
    float px = (float)(w * 16 + k) + dx;
    float x0f = floorf(px);
    float frac = px - x0f;
    int x0 = (int)x0f;
    float w0 = wy * (1.f - frac), w1 = wy * frac;
    if (x0 < 0 || x0 >= NL) w0 = 0.f;
    if (x0 + 1 < 0 || x0 + 1 >= NL) w1 = 0.f;
    int x0c = min(max(x0, 0), NL - 1);
    int x1c = min(max(x0 + 1, 0), NL - 1);
    s_w[rp][k] = make_float2(w0, w1);
    s_i[rp][k] = make_int2(x0c * 64, x1c * 64);
  }
  __syncthreads();

  // Phase 2: vectorized gathers. wave wid -> rows wid*2..+1.
  int c4 = lane >> 2, kq = lane & 3;
#pragma unroll
  for (int rr = 0; rr < 2; ++rr) {
    int rp = wid * 2 + rr;
    const float* xb = x + s_base[rp];
    unsigned short* rowdst = val_ws + (size_t)(row0 + rp) * KD;
#pragma unroll
    for (int p = 0; p < 4; ++p) {
      int k = p * 4 + kq;
      float2 wk = s_w[rp][k];
      int2 ik = s_i[rp][k];
      float4 v0 = *(const float4*)(xb + ik.x + c4 * 4);
      float4 v1 = *(const float4*)(xb + ik.y + c4 * 4);
      ushort4 o;
      o.x = f2bf(wk.x * v0.x + wk.y * v1.x);
      o.y = f2bf(wk.x * v0.y + wk.y * v1.y);
      o.z = f2bf(wk.x * v0.z + wk.y * v1.z);
      o.w = f2bf(wk.x * v0.w + wk.y * v1.w);
      *(ushort4*)(rowdst + c4 * 64 + k * 4) = o;
    }
  }
}

// ---------------------------------------------------------------------------
// main GEMM (R14/R17 body, BK=64 -- best measured): counted-vmcnt dbuf,
// 792 blocks x 128 thr (2 waves of 64x64), BM=128/BN=64, co-XCD octet swizzle
// matched to offsample's producer mapping -> A-operand L2-hit.
// ---------------------------------------------------------------------------
__launch_bounds__(128)
__global__ void gemm_kernel(const unsigned short* __restrict__ val_ws,
                            const unsigned short* __restrict__ wdeft,
                            const float* __restrict__ b_def, const float* __restrict__ pe,
                            float* __restrict__ out) {
  __shared__ unsigned short As[2][128 * 64];   // 2 x 16 KB
  __shared__ unsigned short Bs[2][64 * 64];    // 2 x 8 KB
  int tid = threadIdx.x;
  int flat = blockIdx.x;                           // 0..791
  int w = (flat & 7) * 99 + (flat >> 3);           // bijective (792 = 8*99); chunk -> XCD
  int mt = w >> 3, nt = w & 7;                     // octet w=8m..8m+7 -> same XCD
  int lane = tid & 63, wid = tid >> 6;             // wid 0..1
  int r16 = lane & 15, kg = lane >> 4;
  f4_t acc[4][4] = {};

  int r_st = lane >> 3;
  int j_st = lane & 7;
  const char* aBase = (const char*)val_ws + (size_t)mt * 128 * 2048;
  const char* bBase = (const char*)wdeft + (size_t)nt * 64 * 2048;

  auto STAGE = [&](int ks, int buf) {
#pragma unroll
    for (int i = 0; i < 8; ++i) {                  // A: 16 segs, 8/wave
      int seg = wid * 8 + i;
      int r = seg * 8 + r_st;
      int src_off = ((j_st ^ (r & 7)) << 4);       // inverse-swizzled source chunk
      gl_lds16(aBase + (size_t)r * 2048 + ks * 128 + src_off, &As[buf][seg * 512]);
    }
#pragma unroll
    for (int i = 0; i < 4; ++i) {                  // B: 8 segs, 4/wave
      int seg = wid * 4 + i;
      int r = seg * 8 + r_st;
      int src_off = ((j_st ^ (r & 7)) << 4);
      gl_lds16(bBase + (size_t)r * 2048 + ks * 128 + src_off, &Bs[buf][seg * 512]);
    }
  };

  auto COMPUTE = [&](int buf) {
#pragma unroll
    for (int jb = 0; jb < 8; jb += 4) {            // chunk base: k 0..31 / 32..63
      bf8_t af[4], bf[4];
#pragma unroll
      for (int m = 0; m < 4; ++m) {
        int R = wid * 64 + m * 16 + r16;
        af[m] = *(const bf8_t*)&As[buf][R * 64 + (((jb + kg) ^ (R & 7)) << 3)];
      }
#pragma unroll
      for (int n = 0; n < 4; ++n) {
        int Rc = n * 16 + r16;
        bf[n] = *(const bf8_t*)&Bs[buf][Rc * 64 + (((jb + kg) ^ (Rc & 7)) << 3)];
      }
#pragma unroll
      for (int m = 0; m < 4; ++m)
#pragma unroll
        for (int n = 0; n < 4; ++n)
          acc[m][n] = __builtin_amdgcn_mfma_f32_16x16x32_bf16(af[m], bf[n], acc[m][n], 0, 0, 0);
    }
  };

  STAGE(0, 0);
  asm volatile("s_waitcnt vmcnt(0)" ::: "memory");   // prologue-only full drain
  __builtin_amdgcn_s_barrier();
#pragma unroll
  for (int t = 0; t < 16; ++t) {
    if (t < 15) {
      STAGE(t + 1, (t + 1) & 1);                     // 12 loads into the other buffer
      asm volatile("s_waitcnt vmcnt(12)" ::: "memory");  // tile-t loads landed
    } else {
      asm volatile("s_waitcnt vmcnt(0)" ::: "memory");
    }
    __builtin_amdgcn_s_barrier();                    // all waves: tile t visible
    COMPUTE(t & 1);
    asm volatile("s_waitcnt lgkmcnt(0)" ::: "memory");  // LDS reads complete
    __builtin_amdgcn_sched_barrier(0);               // rule #18 fence
    __builtin_amdgcn_s_barrier();                    // safe to overwrite next step
  }

#pragma unroll
  for (int m = 0; m < 4; ++m)
#pragma unroll
    for (int n = 0; n < 4; ++n)
#pragma unroll
      for (int r = 0; r < 4; ++r) {
        int grow = mt * 128 + wid * 64 + m * 16 + kg * 4 + r;
        int gcol = nt * 64 + n * 16 + r16;
        int bi = grow / NW, wi = grow - bi * NW;
        out[((size_t)(bi * 199 + wi + 1)) * 512 + gcol] =
            acc[m][n][r] + b_def[gcol] + pe[(wi + 1) * 512 + gcol];
      }
}

extern "C" void kernel_launch(void* const* d_in, const int* in_sizes, int n_in,
                              void* d_out, int out_size, void* d_ws, size_t ws_size,
                              hipStream_t stream) {
  const float* x     = (const float*)d_in[0];
  const float* w_off = (const float*)d_in[1];
  const float* b_off = (const float*)d_in[2];
  const float* w_def = (const float*)d_in[3];
  const float* b_def = (const float*)d_in[4];
  const float* cls   = (const float*)d_in[5];
  float* out = (float*)d_out;
  char* ws = (char*)d_ws;
  // workspace layout (bytes):
  unsigned short* val_ws = (unsigned short*)ws;                  // 12672*1024*2 = 25,952,256
  unsigned short* wofft  = (unsigned short*)(ws + 25952256);     // 32*1024*2    = 65,536
  unsigned short* wdeft  = (unsigned short*)(ws + 26017792);     // 512*1024*2   = 1,048,576
  float* pe              = (float*)(ws + 27066368);              // 199*512*4    = 407,552 (end 27,473,920)

  prep_kernel<<<1166, 256, 0, stream>>>(w_off, w_def, cls, wofft, wdeft, pe, out);
  offsample_kernel<<<NM / 16, 512, 0, stream>>>(x, wofft, b_off, val_ws);
  gemm_kernel<<<792, 128, 0, stream>>>(val_ws, wdeft, b_def, pe, out);
}

// Round 21
// 61.086 us; speedup vs baseline: 1.1012x; 1.1012x over previous
//
#include <hip/hip_runtime.h>
#include <math.h>
#include <stdint.h>

#define NB 64
#define NL 3168
#define NC 64
#define ND 512
#define NK 16
#define NW 198
#define NM 12672   // NB*NW rows
#define KD 1024    // contraction dim; layout c*16+k for val/wdeft, k*64+c for x/wofft

typedef __attribute__((ext_vector_type(8))) short bf8_t;   // 8 bf16 (4 VGPR) MFMA A/B frag
typedef __attribute__((ext_vector_type(4))) float f4_t;    // MFMA C/D frag

typedef const unsigned int __attribute__((address_space(1)))* as1_u32p;
typedef unsigned int __attribute__((address_space(3)))* as3_u32p;

__device__ __forceinline__ void gl_lds16(const void* g, void* l) {
  // global -> LDS direct DMA, 16B per lane. LDS dest = wave-uniform base + lane*16.
  __builtin_amdgcn_global_load_lds((as1_u32p)(uintptr_t)g,
                                   (as3_u32p)(unsigned int)(uintptr_t)l, 16, 0, 0);
}

__device__ __forceinline__ unsigned short f2bf(float f) {
  union { float f; unsigned u; } v; v.f = f;
  unsigned r = v.u + 0x7FFFu + ((v.u >> 16) & 1u);
  return (unsigned short)(r >> 16);
}

// ---------------------------------------------------------------------------
// prep: wdeft straight cast (c*16+k layout); wofft mini-transpose; pe; cls.
// ---------------------------------------------------------------------------
__global__ void prep_kernel(const float* __restrict__ w_off, const float* __restrict__ w_def,
                            const float* __restrict__ cls, unsigned short* __restrict__ wofft,
                            unsigned short* __restrict__ wdeft, float* __restrict__ pe,
                            float* __restrict__ out) {
  int id = blockIdx.x * 256 + threadIdx.x;
  if (id < 131072) {
    float4 v = ((const float4*)w_def)[id];
    ushort4 o;
    o.x = f2bf(v.x); o.y = f2bf(v.y); o.z = f2bf(v.z); o.w = f2bf(v.w);
    ((ushort4*)wdeft)[id] = o;
    return;
  }
  id -= 131072;
  if (id < 32768) {
    int o = id >> 10, kc = id & 1023, k = kc >> 6, c = kc & 63;
    wofft[id] = f2bf(w_off[o * 1024 + c * 16 + k]);
    return;
  }
  id -= 32768;
  if (id < 101888) {   // 199 * 512 positional-encoding table
    int pos = id >> 9, d = id & 511;
    int i = d >> 1;
    float freq = expf((float)(2 * i) * (-9.210340371976184f / 512.0f));
    float arg = (float)pos * freq;
    pe[id] = (d & 1) ? cosf(arg) : sinf(arg);
    return;
  }
  id -= 101888;
  {  // cls rows: out[b][0][d] = cls[d] + pe[0][d]
    int b = id >> 9, d = id & 511;
    out[(size_t)(b * 199) * 512 + d] = cls[d] + ((d & 1) ? 1.0f : 0.0f);
  }
}

// ---------------------------------------------------------------------------
// fused off-GEMM + sampling (R17 structure): 792 blocks x 512 thr, matched XCD
// swizzle b=(flat&7)*99+(flat>>3). ONE change vs R17: __launch_bounds__(512,2)
// (R20 showed VGPR_Count=32 -- too few to keep phase-2's 32 gathers in flight)
// + phase-2 loads batched into statically-indexed register arrays so all 32
// independent gathers issue back-to-back before the FMA/pack pass.
// ---------------------------------------------------------------------------
__launch_bounds__(512, 2)
__global__ void offsample_kernel(const float* __restrict__ x,
                                 const unsigned short* __restrict__ wofft,
                                 const float* __restrict__ b_off,
                                 unsigned short* __restrict__ val_ws) {
  __shared__ float partial[8][16][33];
  __shared__ float2 s_w[16][16];   // (w0, w1) per (row, k): bounds folded in
  __shared__ int2   s_i[16][16];   // (x0c*64, x1c*64) clamped gather offsets
  __shared__ int    s_base[16];    // b * NL * NC per row
  int tid = threadIdx.x;
  int lane = tid & 63, wid = tid >> 6;              // wid 0..7
  int r16 = lane & 15, kg = lane >> 4;
  int flat = blockIdx.x;                            // 0..791
  int bsw = (flat & 7) * 99 + (flat >> 3);          // bijective; matches gemm's XCD map
  int row0 = bsw * 16;

  f4_t acc[2] = {};
  const float* arow = x + (size_t)(row0 + r16) * KD + wid * 128;   // lane's A row, K-slice
  const unsigned short* bcol0 = wofft + r16 * KD + wid * 128;
  const unsigned short* bcol1 = wofft + (16 + r16) * KD + wid * 128;

#pragma unroll
  for (int ks = 0; ks < 4; ++ks) {
    int k0 = ks * 32 + kg * 8;
    float4 v0 = *(const float4*)(arow + k0);
    float4 v1 = *(const float4*)(arow + k0 + 4);
    bf8_t a;
    a[0] = (short)f2bf(v0.x); a[1] = (short)f2bf(v0.y);
    a[2] = (short)f2bf(v0.z); a[3] = (short)f2bf(v0.w);
    a[4] = (short)f2bf(v1.x); a[5] = (short)f2bf(v1.y);
    a[6] = (short)f2bf(v1.z); a[7] = (short)f2bf(v1.w);
    bf8_t b0 = *(const bf8_t*)(bcol0 + k0);
    bf8_t b1 = *(const bf8_t*)(bcol1 + k0);
    acc[0] = __builtin_amdgcn_mfma_f32_16x16x32_bf16(a, b0, acc[0], 0, 0, 0);
    acc[1] = __builtin_amdgcn_mfma_f32_16x16x32_bf16(a, b1, acc[1], 0, 0, 0);
  }
  // C layout: col = lane&15 (B col), row = kg*4 + reg (A row)
#pragma unroll
  for (int n = 0; n < 2; ++n)
#pragma unroll
    for (int r = 0; r < 4; ++r)
      partial[wid][kg * 4 + r][n * 16 + r16] = acc[n][r];
  __syncthreads();

  // Phase 1.5: one thread per (row, k) unit.
  if (tid < 256) {
    int rp = tid >> 4, k = tid & 15;
    float dy = b_off[2 * k], dx = b_off[2 * k + 1];
#pragma unroll
    for (int w8 = 0; w8 < 8; ++w8) {
      dy += partial[w8][rp][2 * k];
      dx += partial[w8][rp][2 * k + 1];
    }
    int rg = row0 + rp;
    int b = rg / NW, w = rg - b * NW;
    if (k == 0) s_base[rp] = b * (NL * NC);
    float wy = fmaxf(0.f, 1.f - fabsf(dy));
    float px = (float)(w * 16 + k) + dx;
    float x0f = floorf(px);
    float frac = px - x0f;
    int x0 = (int)x0f;
    float w0 = wy * (1.f - frac), w1 = wy * frac;
    if (x0 < 0 || x0 >= NL) w0 = 0.f;
    if (x0 + 1 < 0 || x0 + 1 >= NL) w1 = 0.f;
    int x0c = min(max(x0, 0), NL - 1);
    int x1c = min(max(x0 + 1, 0), NL - 1);
    s_w[rp][k] = make_float2(w0, w1);
    s_i[rp][k] = make_int2(x0c * 64, x1c * 64);
  }
  __syncthreads();

  // Phase 2: batched gathers -- issue all 32 loads for a row back-to-back
  // (statically-indexed register arrays), then FMA/pack. wave wid -> 2 rows.
#pragma unroll
  for (int rr = 0; rr < 2; ++rr) {
    int rp = wid * 2 + rr;
    const float* xb = x + s_base[rp];
    float v0[16], v1[16];
    float2 wk[16];
#pragma unroll
    for (int k = 0; k < 16; ++k) {
      int2 ik = s_i[rp][k];
      wk[k] = s_w[rp][k];
      v0[k] = xb[ik.x + lane];
      v1[k] = xb[ik.y + lane];
    }
    unsigned short vv[16];
#pragma unroll
    for (int k = 0; k < 16; ++k)
      vv[k] = f2bf(wk[k].x * v0[k] + wk[k].y * v1[k]);
    unsigned int p[8];
#pragma unroll
    for (int i = 0; i < 8; ++i)
      p[i] = (unsigned int)vv[2 * i] | ((unsigned int)vv[2 * i + 1] << 16);
    int rg = row0 + rp;
    uint4* dst = (uint4*)(val_ws + (size_t)rg * KD + lane * 16);
    dst[0] = make_uint4(p[0], p[1], p[2], p[3]);
    dst[1] = make_uint4(p[4], p[5], p[6], p[7]);
  }
}

// ---------------------------------------------------------------------------
// main GEMM (R14/R17 body, unchanged -- best measured): counted-vmcnt dbuf,
// 792 blocks x 128 thr (2 waves of 64x64), BM=128/BN=64/BK=64, co-XCD octet
// swizzle matched to offsample's producer mapping -> A-operand L2-hit.
// ---------------------------------------------------------------------------
__launch_bounds__(128)
__global__ void gemm_kernel(const unsigned short* __restrict__ val_ws,
                            const unsigned short* __restrict__ wdeft,
                            const float* __restrict__ b_def, const float* __restrict__ pe,
                            float* __restrict__ out) {
  __shared__ unsigned short As[2][128 * 64];   // 2 x 16 KB
  __shared__ unsigned short Bs[2][64 * 64];    // 2 x 8 KB
  int tid = threadIdx.x;
  int flat = blockIdx.x;                           // 0..791
  int w = (flat & 7) * 99 + (flat >> 3);           // bijective (792 = 8*99); chunk -> XCD
  int mt = w >> 3, nt = w & 7;                     // octet w=8m..8m+7 -> same XCD
  int lane = tid & 63, wid = tid >> 6;             // wid 0..1
  int r16 = lane & 15, kg = lane >> 4;
  f4_t acc[4][4] = {};

  int r_st = lane >> 3;
  int j_st = lane & 7;
  const char* aBase = (const char*)val_ws + (size_t)mt * 128 * 2048;
  const char* bBase = (const char*)wdeft + (size_t)nt * 64 * 2048;

  auto STAGE = [&](int ks, int buf) {
#pragma unroll
    for (int i = 0; i < 8; ++i) {                  // A: 16 segs, 8/wave
      int seg = wid * 8 + i;
      int r = seg * 8 + r_st;
      int src_off = ((j_st ^ (r & 7)) << 4);       // inverse-swizzled source chunk
      gl_lds16(aBase + (size_t)r * 2048 + ks * 128 + src_off, &As[buf][seg * 512]);
    }
#pragma unroll
    for (int i = 0; i < 4; ++i) {                  // B: 8 segs, 4/wave
      int seg = wid * 4 + i;
      int r = seg * 8 + r_st;
      int src_off = ((j_st ^ (r & 7)) << 4);
      gl_lds16(bBase + (size_t)r * 2048 + ks * 128 + src_off, &Bs[buf][seg * 512]);
    }
  };

  auto COMPUTE = [&](int buf) {
#pragma unroll
    for (int jb = 0; jb < 8; jb += 4) {            // chunk base: k 0..31 / 32..63
      bf8_t af[4], bf[4];
#pragma unroll
      for (int m = 0; m < 4; ++m) {
        int R = wid * 64 + m * 16 + r16;
        af[m] = *(const bf8_t*)&As[buf][R * 64 + (((jb + kg) ^ (R & 7)) << 3)];
      }
#pragma unroll
      for (int n = 0; n < 4; ++n) {
        int Rc = n * 16 + r16;
        bf[n] = *(const bf8_t*)&Bs[buf][Rc * 64 + (((jb + kg) ^ (Rc & 7)) << 3)];
      }
#pragma unroll
      for (int m = 0; m < 4; ++m)
#pragma unroll
        for (int n = 0; n < 4; ++n)
          acc[m][n] = __builtin_amdgcn_mfma_f32_16x16x32_bf16(af[m], bf[n], acc[m][n], 0, 0, 0);
    }
  };

  STAGE(0, 0);
  asm volatile("s_waitcnt vmcnt(0)" ::: "memory");   // prologue-only full drain
  __builtin_amdgcn_s_barrier();
#pragma unroll
  for (int t = 0; t < 16; ++t) {
    if (t < 15) {
      STAGE(t + 1, (t + 1) & 1);                     // 12 loads into the other buffer
      asm volatile("s_waitcnt vmcnt(12)" ::: "memory");  // tile-t loads landed
    } else {
      asm volatile("s_waitcnt vmcnt(0)" ::: "memory");
    }
    __builtin_amdgcn_s_barrier();                    // all waves: tile t visible
    COMPUTE(t & 1);
    asm volatile("s_waitcnt lgkmcnt(0)" ::: "memory");  // LDS reads complete
    __builtin_amdgcn_sched_barrier(0);               // rule #18 fence
    __builtin_amdgcn_s_barrier();                    // safe to overwrite next step
  }

#pragma unroll
  for (int m = 0; m < 4; ++m)
#pragma unroll
    for (int n = 0; n < 4; ++n)
#pragma unroll
      for (int r = 0; r < 4; ++r) {
        int grow = mt * 128 + wid * 64 + m * 16 + kg * 4 + r;
        int gcol = nt * 64 + n * 16 + r16;
        int bi = grow / NW, wi = grow - bi * NW;
        out[((size_t)(bi * 199 + wi + 1)) * 512 + gcol] =
            acc[m][n][r] + b_def[gcol] + pe[(wi + 1) * 512 + gcol];
      }
}

extern "C" void kernel_launch(void* const* d_in, const int* in_sizes, int n_in,
                              void* d_out, int out_size, void* d_ws, size_t ws_size,
                              hipStream_t stream) {
  const float* x     = (const float*)d_in[0];
  const float* w_off = (const float*)d_in[1];
  const float* b_off = (const float*)d_in[2];
  const float* w_def = (const float*)d_in[3];
  const float* b_def = (const float*)d_in[4];
  const float* cls   = (const float*)d_in[5];
  float* out = (float*)d_out;
  char* ws = (char*)d_ws;
  // workspace layout (bytes):
  unsigned short* val_ws = (unsigned short*)ws;                  // 12672*1024*2 = 25,952,256
  unsigned short* wofft  = (unsigned short*)(ws + 25952256);     // 32*1024*2    = 65,536
  unsigned short* wdeft  = (unsigned short*)(ws + 26017792);     // 512*1024*2   = 1,048,576
  float* pe              = (float*)(ws + 27066368);              // 199*512*4    = 407,552 (end 27,473,920)

  prep_kernel<<<1166, 256, 0, stream>>>(w_off, w_def, cls, wofft, wdeft, pe, out);
  offsample_kernel<<<NM / 16, 512, 0, stream>>>(x, wofft, b_off, val_ws);
  gemm_kernel<<<792, 128, 0, stream>>>(val_ws, wdeft, b_def, pe, out);
}